// Round 5
// baseline (151.809 us; speedup 1.0000x reference)
//
#include <hip/hip_runtime.h>
#include <hip/hip_bf16.h>

#define NN 256
#define FI 128
#define FO 64
#define LOG2E 1.4426950408889634f

typedef short s16x8 __attribute__((ext_vector_type(8)));
typedef float f32x4 __attribute__((ext_vector_type(4)));

__device__ __forceinline__ unsigned f2bf1(float x) {
  union { float f; unsigned u; } v; v.f = x;
  unsigned r = v.u + 0x7FFFu + ((v.u >> 16) & 1u);
  return r >> 16;
}
__device__ __forceinline__ unsigned pack2(float a, float b) {
  return f2bf1(a) | (f2bf1(b) << 16);
}
// one-instruction bf16x2 pack (truncation) via v_perm_b32 — alpha only
__device__ __forceinline__ unsigned pktrunc(float lo, float hi) {
  union { float f; unsigned u; } a, b; a.f = hi; b.f = lo;
  return __builtin_amdgcn_perm(a.u, b.u, 0x07060302u);
}
__device__ __forceinline__ float fexp2(float x) {
#if __has_builtin(__builtin_amdgcn_exp2f)
  return __builtin_amdgcn_exp2f(x);
#else
  return exp2f(x);
#endif
}

// ---------------- Kernel 0: adj -> 256-bit row bitmasks (shared by all graphs)
__global__ __launch_bounds__(256) void gat_k0(const float* __restrict__ adj,
                                              unsigned* __restrict__ msk) {
  const int row = blockIdx.x;
  const int wv = threadIdx.x >> 6, lane = threadIdx.x & 63;
  float v = adj[row * NN + wv * 64 + lane];
  unsigned long long b = __ballot(v > 0.f);
  if (lane == 0) {
    msk[row * 8 + wv * 2]     = (unsigned)b;
    msk[row * 8 + wv * 2 + 1] = (unsigned)(b >> 32);
  }
}

// Phase-A subtile: GEMM-1 for 16 rows + wh1/wh2 epilogue + Wh->LDS (frag layout)
__device__ __forceinline__ void phaseA_sub(
    const float4 (&x)[4][2], int w, int s, int m, int q,
    const unsigned short* sWT, const float* sA,
    unsigned short* sWhB, float* sWh1, float* sWh2)
{
  const int R = 32 * w + 16 * s;
  s16x8 af[4];
  #pragma unroll
  for (int kt = 0; kt < 4; ++kt) {
    union { unsigned u[4]; s16x8 v; } pk;
    pk.u[0] = pack2(x[kt][0].x, x[kt][0].y);
    pk.u[1] = pack2(x[kt][0].z, x[kt][0].w);
    pk.u[2] = pack2(x[kt][1].x, x[kt][1].y);
    pk.u[3] = pack2(x[kt][1].z, x[kt][1].w);
    af[kt] = pk.v;
  }
  f32x4 acc[4];
  #pragma unroll
  for (int nt = 0; nt < 4; ++nt) acc[nt] = (f32x4){0.f, 0.f, 0.f, 0.f};
  #pragma unroll
  for (int kt = 0; kt < 4; ++kt)
    #pragma unroll
    for (int nt = 0; nt < 4; ++nt) {
      s16x8 bf = *(const s16x8*)&sWT[(16 * nt + m) * 136 + kt * 32 + q * 8];
      acc[nt] = __builtin_amdgcn_mfma_f32_16x16x32_bf16(af[kt], bf, acc[nt], 0, 0, 0);
    }

  // wh1/wh2 from fp32 acc (acc[nt][r] = Wh[R+4q+r][16nt+m]); store x log2e
  {
    float p1[4] = {0.f,0.f,0.f,0.f}, p2[4] = {0.f,0.f,0.f,0.f};
    #pragma unroll
    for (int nt = 0; nt < 4; ++nt) {
      float a1v = sA[16 * nt + m];
      float a2v = sA[FO + 16 * nt + m];
      #pragma unroll
      for (int r = 0; r < 4; ++r) { p1[r] += acc[nt][r] * a1v; p2[r] += acc[nt][r] * a2v; }
    }
    #pragma unroll
    for (int off = 1; off < 16; off <<= 1)
      #pragma unroll
      for (int r = 0; r < 4; ++r) {
        p1[r] += __shfl_xor(p1[r], off);
        p2[r] += __shfl_xor(p2[r], off);
      }
    if (m == 0) {
      *(float4*)&sWh1[R + 4 * q] =
          make_float4(p1[0]*LOG2E, p1[1]*LOG2E, p1[2]*LOG2E, p1[3]*LOG2E);
      *(float4*)&sWh2[R + 4 * q] =
          make_float4(p2[0]*LOG2E, p2[1]*LOG2E, p2[2]*LOG2E, p2[3]*LOG2E);
    }
  }
  // Wh -> LDS in B-frag chunk layout. chunk(j,o): kt=j>>5(=w), qB=(j>>3)&3,
  // e=j&7, chunk = ((kt*4+nt)*16+m)*4 + (qB ^ (m&3)). RNE pack (error-critical).
  {
    const int qB = (2 * s + (q >> 1)) & 3;
    #pragma unroll
    for (int nt = 0; nt < 4; ++nt) {
      int chunk = ((w * 4 + nt) * 16 + m) * 4 + (qB ^ (m & 3));
      uint2 wrv;
      wrv.x = pack2(acc[nt][0], acc[nt][1]);
      wrv.y = pack2(acc[nt][2], acc[nt][3]);
      *(uint2*)((char*)sWhB + chunk * 16 + (q & 1) * 8) = wrv;
    }
  }
}

// ---------------- Fused kernel: one block per graph, 512 threads (8 waves).
// Phase A: Wh=h@W -> LDS (+wh1/wh2). Phase B: softmax + GEMM-2 + elu.
__global__ __launch_bounds__(512, 4) void gat_fused(
    const float* __restrict__ h, const float* __restrict__ W,
    const float* __restrict__ a, const unsigned* __restrict__ msk,
    float* __restrict__ out)
{
  const int bt   = blockIdx.x;
  const int tid  = threadIdx.x;
  const int lane = tid & 63;
  const int w    = tid >> 6;   // wave 0..7
  const int m    = lane & 15;
  const int q    = lane >> 4;

  __shared__ __align__(16) unsigned short sWhB[64 * 256]; // 32 KB, frag chunks
  __shared__ __align__(16) unsigned short sWT[64 * 136];  // W^T bf16 [o][k]
  __shared__ __align__(16) float sWh1[NN], sWh2[NN];
  __shared__ __align__(16) float sA[2 * FO];

  const float* __restrict__ hB = h + (size_t)bt * NN * FI;

  // subtile-0 h loads in flight while W stages
  float4 x0[4][2];
  #pragma unroll
  for (int kt = 0; kt < 4; ++kt) {
    const float* p = hB + (size_t)(32 * w + m) * FI + kt * 32 + q * 8;
    x0[kt][0] = *(const float4*)p;
    x0[kt][1] = *(const float4*)(p + 4);
  }

  if (tid < 2 * FO) sA[tid] = a[tid];
  for (int idx = tid; idx < FI * FO; idx += 512) {
    int k = idx >> 6, o = idx & 63;
    sWT[o * 136 + k] = (unsigned short)f2bf1(W[idx]);
  }
  __syncthreads();

  // subtile-1 loads issued before subtile-0 compute (overlap)
  float4 x1[4][2];
  #pragma unroll
  for (int kt = 0; kt < 4; ++kt) {
    const float* p = hB + (size_t)(32 * w + 16 + m) * FI + kt * 32 + q * 8;
    x1[kt][0] = *(const float4*)p;
    x1[kt][1] = *(const float4*)(p + 4);
  }

  phaseA_sub(x0, w, 0, m, q, sWT, sA, sWhB, sWh1, sWh2);
  phaseA_sub(x1, w, 1, m, q, sWT, sA, sWhB, sWh1, sWh2);
  __syncthreads();  // publish sWhB / sWh1 / sWh2

  // ---- Phase B: 2 rounds of 16 rows per wave
  float* outB = out + (size_t)bt * NN * FO;
  #pragma unroll
  for (int t = 0; t < 2; ++t) {
    const int R2  = 32 * w + 16 * t;
    const int row = R2 + m;

    const uint4 mka = *(const uint4*)&msk[row * 8];
    const uint4 mkb = *(const uint4*)&msk[row * 8 + 4];
    const unsigned mkw[8] = {mka.x, mka.y, mka.z, mka.w, mkb.x, mkb.y, mkb.z, mkb.w};
    const float w1 = sWh1[row];   // pre-scaled by log2e

    s16x8 A[8];
    float sum = 0.f;
    #pragma unroll
    for (int kt = 0; kt < 8; ++kt) {
      int j0 = kt * 32 + q * 8;
      float4 w20 = *(const float4*)&sWh2[j0];
      float4 w21 = *(const float4*)&sWh2[j0 + 4];
      unsigned wq = mkw[kt] >> (q * 8);
      float p[8];
      const float w2e[8] = {w20.x, w20.y, w20.z, w20.w, w21.x, w21.y, w21.z, w21.w};
      #pragma unroll
      for (int e = 0; e < 8; ++e) {
        float l = w1 + w2e[e];
        l = fmaxf(l, 0.01f * l);                 // leaky-relu (log2e pre-folded)
        union { float f; int i; } u_; u_.f = fexp2(l);
        u_.i &= ((int)(wq << (31 - e))) >> 31;   // adj bit -> 0 / all-ones
        p[e] = u_.f;
        sum += u_.f;
      }
      union { unsigned u[4]; s16x8 v; } pk;
      pk.u[0] = pktrunc(p[0], p[1]);
      pk.u[1] = pktrunc(p[2], p[3]);
      pk.u[2] = pktrunc(p[4], p[5]);
      pk.u[3] = pktrunc(p[6], p[7]);
      A[kt] = pk.v;
    }
    sum += __shfl_xor(sum, 16);
    sum += __shfl_xor(sum, 32);
    const float inv = __builtin_amdgcn_rcpf(sum);

    // GEMM-2: B-frags from LDS (swizzled chunks, uniform bank spread)
    f32x4 acc[4];
    #pragma unroll
    for (int nt = 0; nt < 4; ++nt) acc[nt] = (f32x4){0.f, 0.f, 0.f, 0.f};
    #pragma unroll
    for (int kt = 0; kt < 8; ++kt) {
      #pragma unroll
      for (int nt = 0; nt < 4; ++nt) {
        int chunk = ((kt * 4 + nt) * 16 + m) * 4 + (q ^ (m & 3));
        s16x8 bf = *(const s16x8*)&sWhB[chunk * 8];
        acc[nt] = __builtin_amdgcn_mfma_f32_16x16x32_bf16(A[kt], bf, acc[nt], 0, 0, 0);
      }
    }

    // epilogue: fold 1/sum, elu, store
    float invr[4];
    #pragma unroll
    for (int r = 0; r < 4; ++r) invr[r] = __shfl(inv, 4 * q + r);
    #pragma unroll
    for (int nt = 0; nt < 4; ++nt) {
      int col = 16 * nt + m;
      #pragma unroll
      for (int r = 0; r < 4; ++r) {
        int orow = R2 + 4 * q + r;
        float v = acc[nt][r] * invr[r];
        float ev = fexp2(v * LOG2E) - 1.f;
        v = v > 0.f ? v : ev;
        outB[orow * FO + col] = v;
      }
    }
  }
}

extern "C" void kernel_launch(void* const* d_in, const int* in_sizes, int n_in,
                              void* d_out, int out_size, void* d_ws, size_t ws_size,
                              hipStream_t stream) {
  const float* h   = (const float*)d_in[0];
  const float* W   = (const float*)d_in[1];
  const float* a   = (const float*)d_in[2];
  const float* adj = (const float*)d_in[3];
  float* out = (float*)d_out;

  unsigned* msk = (unsigned*)d_ws;   // 8 KiB

  gat_k0<<<dim3(256), dim3(256), 0, stream>>>(adj, msk);
  gat_fused<<<dim3(512), dim3(512), 0, stream>>>(h, W, a, msk, out);
}

// Round 6
// 134.274 us; speedup vs baseline: 1.1306x; 1.1306x over previous
//
#include <hip/hip_runtime.h>
#include <hip/hip_bf16.h>

#define NN 256
#define FI 128
#define FO 64
#define LOG2E 1.4426950408889634f

typedef short s16x8 __attribute__((ext_vector_type(8)));
typedef float f32x4 __attribute__((ext_vector_type(4)));

__device__ __forceinline__ unsigned f2bf1(float x) {
  union { float f; unsigned u; } v; v.f = x;
  unsigned r = v.u + 0x7FFFu + ((v.u >> 16) & 1u);
  return r >> 16;
}
__device__ __forceinline__ unsigned pack2(float a, float b) {
  return f2bf1(a) | (f2bf1(b) << 16);
}
// one-instruction bf16x2 pack (truncation) via v_perm_b32 — alpha only
__device__ __forceinline__ unsigned pktrunc(float lo, float hi) {
  union { float f; unsigned u; } a, b; a.f = hi; b.f = lo;
  return __builtin_amdgcn_perm(a.u, b.u, 0x07060302u);
}
__device__ __forceinline__ float fexp2(float x) {
#if __has_builtin(__builtin_amdgcn_exp2f)
  return __builtin_amdgcn_exp2f(x);
#else
  return exp2f(x);
#endif
}

// ---------------- Kernel 0: adj -> 256-bit row bitmasks (shared by all graphs)
__global__ __launch_bounds__(256) void gat_k0(const float* __restrict__ adj,
                                              unsigned* __restrict__ msk) {
  const int row = blockIdx.x;
  const int wv = threadIdx.x >> 6, lane = threadIdx.x & 63;
  float v = adj[row * NN + wv * 64 + lane];
  unsigned long long b = __ballot(v > 0.f);
  if (lane == 0) {
    msk[row * 8 + wv * 2]     = (unsigned)b;
    msk[row * 8 + wv * 2 + 1] = (unsigned)(b >> 32);
  }
}

// Phase-A subtile: GEMM-1 for 16 rows + wh1/wh2 epilogue + Wh->LDS (frag layout)
__device__ __forceinline__ void phaseA_sub(
    const float4 (&x)[4][2], int w, int s, int m, int q,
    const unsigned short* sWT, const float* sA,
    unsigned short* sWhB, float* sWh1, float* sWh2)
{
  const int R = 32 * w + 16 * s;
  s16x8 af[4];
  #pragma unroll
  for (int kt = 0; kt < 4; ++kt) {
    union { unsigned u[4]; s16x8 v; } pk;
    pk.u[0] = pack2(x[kt][0].x, x[kt][0].y);
    pk.u[1] = pack2(x[kt][0].z, x[kt][0].w);
    pk.u[2] = pack2(x[kt][1].x, x[kt][1].y);
    pk.u[3] = pack2(x[kt][1].z, x[kt][1].w);
    af[kt] = pk.v;
  }
  f32x4 acc[4];
  #pragma unroll
  for (int nt = 0; nt < 4; ++nt) acc[nt] = (f32x4){0.f, 0.f, 0.f, 0.f};
  #pragma unroll
  for (int kt = 0; kt < 4; ++kt)
    #pragma unroll
    for (int nt = 0; nt < 4; ++nt) {
      s16x8 bf = *(const s16x8*)&sWT[(16 * nt + m) * 136 + kt * 32 + q * 8];
      acc[nt] = __builtin_amdgcn_mfma_f32_16x16x32_bf16(af[kt], bf, acc[nt], 0, 0, 0);
    }

  // wh1/wh2 from fp32 acc (acc[nt][r] = Wh[R+4q+r][16nt+m]); store x log2e
  {
    float p1[4] = {0.f,0.f,0.f,0.f}, p2[4] = {0.f,0.f,0.f,0.f};
    #pragma unroll
    for (int nt = 0; nt < 4; ++nt) {
      float a1v = sA[16 * nt + m];
      float a2v = sA[FO + 16 * nt + m];
      #pragma unroll
      for (int r = 0; r < 4; ++r) { p1[r] += acc[nt][r] * a1v; p2[r] += acc[nt][r] * a2v; }
    }
    #pragma unroll
    for (int off = 1; off < 16; off <<= 1)
      #pragma unroll
      for (int r = 0; r < 4; ++r) {
        p1[r] += __shfl_xor(p1[r], off);
        p2[r] += __shfl_xor(p2[r], off);
      }
    if (m == 0) {
      *(float4*)&sWh1[R + 4 * q] =
          make_float4(p1[0]*LOG2E, p1[1]*LOG2E, p1[2]*LOG2E, p1[3]*LOG2E);
      *(float4*)&sWh2[R + 4 * q] =
          make_float4(p2[0]*LOG2E, p2[1]*LOG2E, p2[2]*LOG2E, p2[3]*LOG2E);
    }
  }
  // Wh -> LDS in frag chunk layout: for element (o, j):
  // chunk = ((ktj*4 + (o>>4))*16 + (o&15))*4 + (qj ^ (o&3)), ktj=j>>5, qj=(j>>3)&3
  {
    const int qB = (2 * s + (q >> 1)) & 3;
    #pragma unroll
    for (int nt = 0; nt < 4; ++nt) {
      int chunk = ((w * 4 + nt) * 16 + m) * 4 + (qB ^ (m & 3));
      uint2 wrv;
      wrv.x = pack2(acc[nt][0], acc[nt][1]);
      wrv.y = pack2(acc[nt][2], acc[nt][3]);
      *(uint2*)((char*)sWhB + chunk * 16 + (q & 1) * 8) = wrv;
    }
  }
}

// ---------------- Fused kernel: one block per graph, 512 threads (8 waves).
// Phase A: Wh=h@W -> LDS (+wh1/wh2). Phase B: softmax + GEMM-2 (operand-swapped:
// out^T-tiles = Wh^T @ alpha^T, so alpha's softmax register layout IS the
// B-fragment and each lane's C holds 4 consecutive out columns) + elu.
__global__ __launch_bounds__(512)
__attribute__((amdgpu_waves_per_eu(3, 4)))
void gat_fused(
    const float* __restrict__ h, const float* __restrict__ W,
    const float* __restrict__ a, const unsigned* __restrict__ msk,
    float* __restrict__ out)
{
  const int bt   = blockIdx.x;
  const int tid  = threadIdx.x;
  const int lane = tid & 63;
  const int w    = tid >> 6;   // wave 0..7
  const int m    = lane & 15;
  const int q    = lane >> 4;

  __shared__ __align__(16) unsigned short sWhB[64 * 256]; // 32 KB, frag chunks
  __shared__ __align__(16) unsigned short sWT[64 * 136];  // W^T bf16 [o][k]
  __shared__ __align__(16) float sWh1[NN], sWh2[NN];
  __shared__ __align__(16) float sA[2 * FO];

  const float* __restrict__ hB = h + (size_t)bt * NN * FI;

  // subtile-0 h loads in flight while W stages
  float4 x0[4][2];
  #pragma unroll
  for (int kt = 0; kt < 4; ++kt) {
    const float* p = hB + (size_t)(32 * w + m) * FI + kt * 32 + q * 8;
    x0[kt][0] = *(const float4*)p;
    x0[kt][1] = *(const float4*)(p + 4);
  }
  // subtile-1 loads also issued up-front (VGPR budget now allows both)
  float4 x1[4][2];
  #pragma unroll
  for (int kt = 0; kt < 4; ++kt) {
    const float* p = hB + (size_t)(32 * w + 16 + m) * FI + kt * 32 + q * 8;
    x1[kt][0] = *(const float4*)p;
    x1[kt][1] = *(const float4*)(p + 4);
  }

  if (tid < 2 * FO) sA[tid] = a[tid];
  for (int idx = tid; idx < FI * FO; idx += 512) {
    int k = idx >> 6, o = idx & 63;
    sWT[o * 136 + k] = (unsigned short)f2bf1(W[idx]);
  }
  __syncthreads();

  phaseA_sub(x0, w, 0, m, q, sWT, sA, sWhB, sWh1, sWh2);
  phaseA_sub(x1, w, 1, m, q, sWT, sA, sWhB, sWh1, sWh2);
  __syncthreads();  // publish sWhB / sWh1 / sWh2

  // ---- Phase B: 2 rounds of 16 attention rows per wave
  float* outB = out + (size_t)bt * NN * FO;
  #pragma unroll
  for (int t = 0; t < 2; ++t) {
    const int R2  = 32 * w + 16 * t;
    const int row = R2 + m;            // this lane's attention row

    const uint4 mka = *(const uint4*)&msk[row * 8];
    const uint4 mkb = *(const uint4*)&msk[row * 8 + 4];
    const unsigned mkw[8] = {mka.x, mka.y, mka.z, mka.w, mkb.x, mkb.y, mkb.z, mkb.w};
    const float w1 = sWh1[row];        // pre-scaled by log2e

    s16x8 A[8];                        // alpha, B-fragment layout
    float sum = 0.f;
    #pragma unroll
    for (int kt = 0; kt < 8; ++kt) {
      int j0 = kt * 32 + q * 8;
      float4 w20 = *(const float4*)&sWh2[j0];
      float4 w21 = *(const float4*)&sWh2[j0 + 4];
      unsigned wq = mkw[kt] >> (q * 8);
      float p[8];
      const float w2e[8] = {w20.x, w20.y, w20.z, w20.w, w21.x, w21.y, w21.z, w21.w};
      #pragma unroll
      for (int e = 0; e < 8; ++e) {
        float l = w1 + w2e[e];
        l = fmaxf(l, 0.01f * l);                 // leaky-relu (log2e pre-folded)
        union { float f; int i; } u_; u_.f = fexp2(l);
        u_.i &= ((int)(wq << (31 - e))) >> 31;   // adj bit -> 0 / all-ones
        p[e] = u_.f;
        sum += u_.f;
      }
      union { unsigned u[4]; s16x8 v; } pk;
      pk.u[0] = pktrunc(p[0], p[1]);
      pk.u[1] = pktrunc(p[2], p[3]);
      pk.u[2] = pktrunc(p[4], p[5]);
      pk.u[3] = pktrunc(p[6], p[7]);
      A[kt] = pk.v;
    }
    sum += __shfl_xor(sum, 16);
    sum += __shfl_xor(sum, 32);
    const float inv = __builtin_amdgcn_rcpf(sum);  // per-lane row inv — no bcast needed

    // GEMM-2 swapped: D = Wh^T(A-op) @ alpha^T(B-op). A-frag read uses the
    // identical chunk expression with ot in place of nt.
    f32x4 acc[4];
    #pragma unroll
    for (int ot = 0; ot < 4; ++ot) acc[ot] = (f32x4){0.f, 0.f, 0.f, 0.f};
    #pragma unroll
    for (int kt = 0; kt < 8; ++kt) {
      #pragma unroll
      for (int ot = 0; ot < 4; ++ot) {
        int chunk = ((kt * 4 + ot) * 16 + m) * 4 + (q ^ (m & 3));
        s16x8 whf = *(const s16x8*)&sWhB[chunk * 8];
        acc[ot] = __builtin_amdgcn_mfma_f32_16x16x32_bf16(whf, A[kt], acc[ot], 0, 0, 0);
      }
    }

    // epilogue: lane(m,q) holds out[row][16ot+4q .. +3] -> float4 stores
    #pragma unroll
    for (int ot = 0; ot < 4; ++ot) {
      float4 v4;
      float* vp = (float*)&v4;
      #pragma unroll
      for (int r = 0; r < 4; ++r) {
        float v = acc[ot][r] * inv;
        float ev = fexp2(v * LOG2E) - 1.f;
        vp[r] = v > 0.f ? v : ev;
      }
      *(float4*)&outB[row * FO + 16 * ot + 4 * q] = v4;
    }
  }
}

extern "C" void kernel_launch(void* const* d_in, const int* in_sizes, int n_in,
                              void* d_out, int out_size, void* d_ws, size_t ws_size,
                              hipStream_t stream) {
  const float* h   = (const float*)d_in[0];
  const float* W   = (const float*)d_in[1];
  const float* a   = (const float*)d_in[2];
  const float* adj = (const float*)d_in[3];
  float* out = (float*)d_out;

  unsigned* msk = (unsigned*)d_ws;   // 8 KiB

  gat_k0<<<dim3(256), dim3(256), 0, stream>>>(adj, msk);
  gat_fused<<<dim3(512), dim3(512), 0, stream>>>(h, W, a, msk, out);
}